// Round 2
// baseline (172.970 us; speedup 1.0000x reference)
//
#include <hip/hip_runtime.h>
#include <hip/hip_fp16.h>

#define NB 4
#define NT 16
#define NN 2048
#define NM 64
#define NK 32
#define NC 1024
#define MB 8   // anchors (m) per block in group kernel

// ROCm 7.2 hip_fp16.h has no __hmax2 — emit v_pk_max_f16 directly.
static __device__ inline __half2 h2max(__half2 a, __half2 b) {
    unsigned int ai = *(unsigned int*)&a, bi = *(unsigned int*)&b, di;
    asm("v_pk_max_f16 %0, %1, %2" : "=v"(di) : "v"(ai), "v"(bi));
    return *(__half2*)&di;
}

// ---------------------------------------------------------------------------
// Kernel A: furthest point sampling, one block per (b,t) frame.
// Bit-exact vs reference: d2 via __fmul_rn/__fadd_rn (no contraction),
// argmax = first occurrence of max (strict >, tie -> smaller index).
// Writes anchor coords straight into d_out's new_xyzs region.
// ---------------------------------------------------------------------------
__global__ __launch_bounds__(1024) void fps_kernel(const float* __restrict__ xyzs,
                                                   float* __restrict__ out_xyz) {
    const int bt = blockIdx.x;
    const float* pts = xyzs + (size_t)bt * NN * 3;
    __shared__ float sP[NN * 3];
    __shared__ float sRedV[16];
    __shared__ int   sRedI[16];
    __shared__ int   sLast;
    const int tid = threadIdx.x;
    for (int i = tid; i < NN * 3; i += 1024) sP[i] = pts[i];
    __syncthreads();
    const int lane = tid & 63;
    const int wave = tid >> 6;
    const int n1 = tid + 1024;
    const float p0x = sP[tid * 3 + 0], p0y = sP[tid * 3 + 1], p0z = sP[tid * 3 + 2];
    const float p1x = sP[n1 * 3 + 0],  p1y = sP[n1 * 3 + 1],  p1z = sP[n1 * 3 + 2];
    float d20 = 1e10f, d21 = 1e10f;
    int last = 0;
    for (int it = 0; it < NM; ++it) {
        // anchor for slot `it` is `last` (reference scan emits pre-update last)
        if (tid < 3) out_xyz[(bt * NM + it) * 3 + tid] = sP[last * 3 + tid];
        const float lx = sP[last * 3 + 0], ly = sP[last * 3 + 1], lz = sP[last * 3 + 2];
        {
            const float dx = __fsub_rn(p0x, lx), dy = __fsub_rn(p0y, ly), dz = __fsub_rn(p0z, lz);
            const float d = __fadd_rn(__fadd_rn(__fmul_rn(dx, dx), __fmul_rn(dy, dy)), __fmul_rn(dz, dz));
            d20 = fminf(d20, d);
        }
        {
            const float dx = __fsub_rn(p1x, lx), dy = __fsub_rn(p1y, ly), dz = __fsub_rn(p1z, lz);
            const float d = __fadd_rn(__fadd_rn(__fmul_rn(dx, dx), __fmul_rn(dy, dy)), __fmul_rn(dz, dz));
            d21 = fminf(d21, d);
        }
        float v; int bi;
        if (d21 > d20) { v = d21; bi = n1; } else { v = d20; bi = tid; }  // tie -> smaller idx
        #pragma unroll
        for (int off = 32; off > 0; off >>= 1) {
            const float ov = __shfl_xor(v, off, 64);
            const int   oi = __shfl_xor(bi, off, 64);
            if (ov > v || (ov == v && oi < bi)) { v = ov; bi = oi; }
        }
        if (lane == 0) { sRedV[wave] = v; sRedI[wave] = bi; }
        __syncthreads();
        if (wave == 0) {
            float v2 = (lane < 16) ? sRedV[lane] : -1.0f;
            int  bi2 = (lane < 16) ? sRedI[lane] : 0x7fffffff;
            #pragma unroll
            for (int off = 8; off > 0; off >>= 1) {
                const float ov = __shfl_xor(v2, off, 64);
                const int   oi = __shfl_xor(bi2, off, 64);
                if (ov > v2 || (ov == v2 && oi < bi2)) { v2 = ov; bi2 = oi; }
            }
            if (lane == 0) sLast = bi2;
        }
        __syncthreads();
        last = sLast;
    }
}

// ---------------------------------------------------------------------------
// Kernel B: ball query (ballot scan, first-K in index order) + fp16-packed
// 1x1 conv + k-maxpool + tap-sum, written directly in [B,T,C,M] layout.
// One block per (bt, 8 consecutive m). 512 threads: 2 channels/thread.
// ---------------------------------------------------------------------------
__global__ __launch_bounds__(512) void group_kernel(const float* __restrict__ xyzs,
                                                    const float* __restrict__ wd,
                                                    const float* __restrict__ anchors,
                                                    float* __restrict__ feat) {
    const int blk = blockIdx.x;       // 512 blocks
    const int bt  = blk >> 3;
    const int m0  = (blk & 7) * MB;
    const int b   = bt >> 4;          // / NT
    const int t   = bt & 15;          // % NT
    __shared__ float sDisp[MB][3][NK][3];                  // f32 displacements
    __shared__ __align__(16) __half2 sH[MB][3][3][NK / 2]; // [m][tap][comp][kpair]
    const int tid  = threadIdx.x;
    const int lane = tid & 63;
    const int wave = tid >> 6;        // 0..7

    // --- phase 1: ball query, 24 (m,tap) queries spread over 8 waves ---
    for (int q = wave; q < MB * 3; q += 8) {
        const int mq  = q / 3;
        const int tap = q - mq * 3;
        const float* ap = anchors + ((size_t)bt * NM + m0 + mq) * 3;
        const float ax = ap[0], ay = ap[1], az = ap[2];
        int tsrc = t + tap - 1;
        tsrc = tsrc < 0 ? 0 : (tsrc > NT - 1 ? NT - 1 : tsrc);
        const float* npts = xyzs + ((size_t)(b * NT + tsrc)) * NN * 3;
        int cnt = 0;
        for (int r = 0; r < NN / 64 && cnt < NK; ++r) {
            const int n = r * 64 + lane;
            const float dx = __fsub_rn(npts[n * 3 + 0], ax);
            const float dy = __fsub_rn(npts[n * 3 + 1], ay);
            const float dz = __fsub_rn(npts[n * 3 + 2], az);
            const float d2 = __fadd_rn(__fadd_rn(__fmul_rn(dx, dx), __fmul_rn(dy, dy)), __fmul_rn(dz, dz));
            const bool valid = d2 < 0.49f;   // f32(0.7*0.7), matches reference rounding
            const unsigned long long mask = __ballot(valid);
            const int pos = cnt + (int)__popcll(mask & ((1ull << lane) - 1ull));
            if (valid && pos < NK) {
                sDisp[mq][tap][pos][0] = dx;
                sDisp[mq][tap][pos][1] = dy;
                sDisp[mq][tap][pos][2] = dz;
            }
            cnt += (int)__popcll(mask);
        }
        if (cnt < NK) {  // pad with first valid disp (or neigh[0]-anchor if none)
            float fx, fy, fz;
            if (cnt > 0) {
                fx = sDisp[mq][tap][0][0];
                fy = sDisp[mq][tap][0][1];
                fz = sDisp[mq][tap][0][2];
            } else {
                fx = __fsub_rn(npts[0], ax);
                fy = __fsub_rn(npts[1], ay);
                fz = __fsub_rn(npts[2], az);
            }
            if (lane >= cnt && lane < NK) {
                sDisp[mq][tap][lane][0] = fx;
                sDisp[mq][tap][lane][1] = fy;
                sDisp[mq][tap][lane][2] = fz;
            }
        }
    }
    __syncthreads();

    // --- phase 1.5: repack f32 disp -> half2 pairs along k (RNE) ---
    for (int i = tid; i < MB * 3 * 3 * (NK / 2); i += 512) {
        const int j = i & 15;
        int r = i >> 4;
        const int c = r % 3; r /= 3;
        const int tap = r % 3;
        const int m = r / 3;
        sH[m][tap][c][j] = __float22half2_rn(
            make_float2(sDisp[m][tap][2 * j][c], sDisp[m][tap][2 * j + 1][c]));
    }
    __syncthreads();

    // --- phase 2: per-channel max-dot, 2 channels per thread ---
    const float4 w0 = ((const float4*)wd)[tid];
    const float4 w1 = ((const float4*)wd)[tid + 512];
    const __half2 w0x = __float2half2_rn(w0.x), w0y = __float2half2_rn(w0.y), w0z = __float2half2_rn(w0.z);
    const __half2 w1x = __float2half2_rn(w1.x), w1y = __float2half2_rn(w1.y), w1z = __float2half2_rn(w1.z);

    float vals0[MB], vals1[MB];
    #pragma unroll
    for (int m = 0; m < MB; ++m) {
        float acc0 = 0.f, acc1 = 0.f;
        #pragma unroll
        for (int tap = 0; tap < 3; ++tap) {
            const __half2* hp = &sH[m][tap][0][0];
            __half2 dx = hp[0], dy = hp[16], dz = hp[32];
            __half2 a0 = __hfma2(w0x, dx, __hfma2(w0y, dy, __hmul2(w0z, dz)));
            __half2 a1 = __hfma2(w1x, dx, __hfma2(w1y, dy, __hmul2(w1z, dz)));
            #pragma unroll
            for (int j = 1; j < 16; ++j) {
                dx = hp[j]; dy = hp[16 + j]; dz = hp[32 + j];
                const __half2 s0 = __hfma2(w0x, dx, __hfma2(w0y, dy, __hmul2(w0z, dz)));
                const __half2 s1 = __hfma2(w1x, dx, __hfma2(w1y, dy, __hmul2(w1z, dz)));
                a0 = h2max(a0, s0);
                a1 = h2max(a1, s1);
            }
            const float dtf = (float)(tap - 1);
            const float mx0 = fmaxf(__low2float(a0), __high2float(a0));
            const float mx1 = fmaxf(__low2float(a1), __high2float(a1));
            acc0 += fmaxf(0.f, mx0 + w0.w * dtf);   // relu/max/+const commute
            acc1 += fmaxf(0.f, mx1 + w1.w * dtf);
        }
        vals0[m] = acc0;
        vals1[m] = acc1;
    }
    // direct [B,T,C,M] store: each thread writes two 32B-contiguous runs
    float* o0 = feat + ((size_t)bt * NC + tid) * NM + m0;
    float* o1 = feat + ((size_t)bt * NC + tid + 512) * NM + m0;
    #pragma unroll
    for (int i = 0; i < MB / 4; ++i) {
        ((float4*)o0)[i] = make_float4(vals0[4 * i + 0], vals0[4 * i + 1], vals0[4 * i + 2], vals0[4 * i + 3]);
        ((float4*)o1)[i] = make_float4(vals1[4 * i + 0], vals1[4 * i + 1], vals1[4 * i + 2], vals1[4 * i + 3]);
    }
}

extern "C" void kernel_launch(void* const* d_in, const int* in_sizes, int n_in,
                              void* d_out, int out_size, void* d_ws, size_t ws_size,
                              hipStream_t stream) {
    const float* xyzs = (const float*)d_in[0];
    const float* wd   = (const float*)d_in[1];
    float* out_xyz = (float*)d_out;
    float* featp   = out_xyz + NB * NT * NM * 3;   // new_features region
    hipLaunchKernelGGL(fps_kernel, dim3(NB * NT), dim3(1024), 0, stream, xyzs, out_xyz);
    hipLaunchKernelGGL(group_kernel, dim3(NB * NT * (NM / MB)), dim3(512), 0, stream,
                       xyzs, wd, out_xyz, featp);
}

// Round 3
// 133.551 us; speedup vs baseline: 1.2952x; 1.2952x over previous
//
#include <hip/hip_runtime.h>
#include <hip/hip_fp16.h>

#define NB 4
#define NT 16
#define NN 2048
#define NM 64
#define NK 32
#define NC 1024

// ROCm 7.2 hip_fp16.h has no __hmax2 — emit v_pk_max_f16 directly.
static __device__ inline __half2 h2max(__half2 a, __half2 b) {
    unsigned int ai = *(unsigned int*)&a, bi = *(unsigned int*)&b, di;
    asm("v_pk_max_f16 %0, %1, %2" : "=v"(di) : "v"(ai), "v"(bi));
    return *(__half2*)&di;
}
static __device__ inline unsigned long long u64max(unsigned long long a, unsigned long long b) {
    return a > b ? a : b;
}

// ---------------------------------------------------------------------------
// Kernel A: FPS, one block (256 thr = 4 waves) per frame. 8 points/lane in
// registers. Key trick: (d2,idx) packed as u64 (d2>=0 -> float bits monotonic;
// low32 = 2047-idx -> max picks smallest index on ties, matching jnp.argmax).
// Anchors buffered in LDS, ONE global write at the end (no vmcnt drain before
// the per-round barrier). One barrier/round via parity double-buffer.
// Arithmetic (_rn, no FMA) identical to the R2-verified bit-exact version.
// ---------------------------------------------------------------------------
__global__ __launch_bounds__(256) void fps_kernel(const float* __restrict__ xyzs,
                                                  float* __restrict__ out_xyz) {
    const int bt = blockIdx.x;
    const float* pts = xyzs + (size_t)bt * NN * 3;
    __shared__ float sX[NN], sY[NN], sZ[NN];
    __shared__ unsigned long long sPart[2][4];
    __shared__ float sAnchor[NM * 3];
    const int tid = threadIdx.x;
    const int lane = tid & 63, wave = tid >> 6;
    float px[8], py[8], pz[8], d2[8];
    #pragma unroll
    for (int j = 0; j < 8; ++j) {
        const int p = tid + 256 * j;
        px[j] = pts[p * 3 + 0];
        py[j] = pts[p * 3 + 1];
        pz[j] = pts[p * 3 + 2];
        sX[p] = px[j]; sY[p] = py[j]; sZ[p] = pz[j];
        d2[j] = 1e10f;
    }
    __syncthreads();
    int last = 0;
    for (int it = 0; it < NM; ++it) {
        const float lx = sX[last], ly = sY[last], lz = sZ[last];
        if (tid == 0) {
            sAnchor[it * 3 + 0] = lx; sAnchor[it * 3 + 1] = ly; sAnchor[it * 3 + 2] = lz;
        }
        float bv = -1.0f; int bj = 0;
        #pragma unroll
        for (int j = 0; j < 8; ++j) {
            const float dx = __fsub_rn(px[j], lx), dy = __fsub_rn(py[j], ly), dz = __fsub_rn(pz[j], lz);
            const float d = __fadd_rn(__fadd_rn(__fmul_rn(dx, dx), __fmul_rn(dy, dy)), __fmul_rn(dz, dz));
            d2[j] = fminf(d2[j], d);
            if (d2[j] > bv) { bv = d2[j]; bj = j; }  // strict > keeps smallest j on tie
        }
        unsigned long long key = ((unsigned long long)__float_as_uint(bv) << 32)
                               | (unsigned)(NN - 1 - (tid + 256 * bj));
        #pragma unroll
        for (int off = 32; off > 0; off >>= 1)
            key = u64max(key, __shfl_xor(key, off, 64));
        if (lane == 0) sPart[it & 1][wave] = key;
        __syncthreads();
        key = u64max(u64max(sPart[it & 1][0], sPart[it & 1][1]),
                     u64max(sPart[it & 1][2], sPart[it & 1][3]));
        last = NN - 1 - (int)(key & 0xffffffffull);
    }
    __syncthreads();
    for (int i = tid; i < NM * 3; i += 256)
        out_xyz[bt * NM * 3 + i] = sAnchor[i];
}

// ---------------------------------------------------------------------------
// Kernel B: one WAVE per (bt,m): 256 blocks x 1024 thr (16 waves = 16 m's),
// exactly 1 block per CU. Per tap: intra-wave ballot ball query -> LDS f32 ->
// repack half2 -> 12x ds_read_b128 broadcast into 48 VGPRs -> 16 channels/lane
// of pk-fp16 dot+max (2 instr per k). No barriers until the output transpose.
// Output staged in 17-padded LDS (conflict-free), stored as full 64B lines.
// ---------------------------------------------------------------------------
__global__ __launch_bounds__(1024) void group_kernel(const float* __restrict__ xyzs,
                                                     const float* __restrict__ wd,
                                                     const float* __restrict__ anchors,
                                                     float* __restrict__ feat) {
    const int blk = blockIdx.x;          // 256 blocks
    const int bt = blk >> 2;
    const int m0 = (blk & 3) * 16;
    const int b = bt >> 4, t = bt & 15;
    __shared__ float sOut[NC * 17];                     // 69632 B transpose buffer
    __shared__ float sDispF[16][3][NK];                 // 6144 B per-wave f32 disp
    __shared__ __align__(16) unsigned int sH[16][48];   // 3072 B per-wave half2 disp
    const int tid = threadIdx.x;
    const int lane = tid & 63, w = tid >> 6;
    const int m = m0 + w;
    const float ax = anchors[(bt * NM + m) * 3 + 0];
    const float ay = anchors[(bt * NM + m) * 3 + 1];
    const float az = anchors[(bt * NM + m) * 3 + 2];
    float acc[16];
    #pragma unroll
    for (int i = 0; i < 16; ++i) acc[i] = 0.0f;

    #pragma unroll 1
    for (int tap = 0; tap < 3; ++tap) {
        int tsrc = t + tap - 1;
        tsrc = tsrc < 0 ? 0 : (tsrc > NT - 1 ? NT - 1 : tsrc);
        const float* npts = xyzs + ((size_t)(b * NT + tsrc)) * NN * 3;
        // --- ball query (intra-wave, ballot scan, early exit) ---
        int cnt = 0;
        for (int r = 0; r < NN / 64 && cnt < NK; ++r) {
            const int n = r * 64 + lane;
            const float dx = __fsub_rn(npts[n * 3 + 0], ax);
            const float dy = __fsub_rn(npts[n * 3 + 1], ay);
            const float dz = __fsub_rn(npts[n * 3 + 2], az);
            const float d2v = __fadd_rn(__fadd_rn(__fmul_rn(dx, dx), __fmul_rn(dy, dy)), __fmul_rn(dz, dz));
            const bool valid = d2v < 0.49f;   // f32(0.7*0.7)
            const unsigned long long mask = __ballot(valid);
            const int pos = cnt + (int)__popcll(mask & ((1ull << lane) - 1ull));
            if (valid && pos < NK) {
                sDispF[w][0][pos] = dx; sDispF[w][1][pos] = dy; sDispF[w][2][pos] = dz;
            }
            cnt += (int)__popcll(mask);
        }
        if (cnt < NK) {   // pad with first valid disp (or neigh[0]-anchor if none)
            float fx, fy, fz;
            if (cnt > 0) {
                fx = sDispF[w][0][0]; fy = sDispF[w][1][0]; fz = sDispF[w][2][0];
            } else {
                fx = __fsub_rn(npts[0], ax); fy = __fsub_rn(npts[1], ay); fz = __fsub_rn(npts[2], az);
            }
            if (lane >= cnt && lane < NK) {
                sDispF[w][0][lane] = fx; sDispF[w][1][lane] = fy; sDispF[w][2][lane] = fz;
            }
        }
        // --- repack f32 -> half2 pairs along k (lanes 0..47) ---
        if (lane < 48) {
            const int c = lane >> 4, j = lane & 15;
            const float f0 = sDispF[w][c][2 * j], f1 = sDispF[w][c][2 * j + 1];
            __half2 hv = __float22half2_rn(make_float2(f0, f1));
            sH[w][c * 16 + j] = *(unsigned int*)&hv;
        }
        // --- broadcast-load all 48 half2 into registers (12x b128) ---
        unsigned int hw_[48];
        #pragma unroll
        for (int i = 0; i < 12; ++i) {
            uint4 u = ((const uint4*)&sH[w][0])[i];
            hw_[4 * i + 0] = u.x; hw_[4 * i + 1] = u.y; hw_[4 * i + 2] = u.z; hw_[4 * i + 3] = u.w;
        }
        const float dtf = (float)(tap - 1);
        // --- 16 channels per lane: pk-fp16 dot + k-maxpool ---
        #pragma unroll
        for (int i = 0; i < 16; ++i) {
            const int c = lane + 64 * i;
            const float4 wv = ((const float4*)wd)[c];
            const __half2 wx = __float2half2_rn(wv.x);
            const __half2 wy = __float2half2_rn(wv.y);
            const __half2 wz = __float2half2_rn(wv.z);
            __half2 a;
            #pragma unroll
            for (int j = 0; j < 16; ++j) {
                const __half2 hx = *(const __half2*)&hw_[j];
                const __half2 hy = *(const __half2*)&hw_[16 + j];
                const __half2 hz = *(const __half2*)&hw_[32 + j];
                const __half2 s = __hfma2(wx, hx, __hfma2(wy, hy, __hmul2(wz, hz)));
                a = (j == 0) ? s : h2max(a, s);
            }
            const float mx = fmaxf(__low2float(a), __high2float(a));
            acc[i] += fmaxf(0.0f, mx + wv.w * dtf);   // relu/max/+const commute
        }
    }
    // --- transpose through LDS, store full 64B lines ---
    #pragma unroll
    for (int i = 0; i < 16; ++i)
        sOut[(lane + 64 * i) * 17 + w] = acc[i];
    __syncthreads();
    {
        const int c = tid;   // 1024 rows, one per thread
        float* dst = feat + ((size_t)bt * NC + c) * NM + m0;
        const float* src = &sOut[c * 17];
        #pragma unroll
        for (int r = 0; r < 4; ++r) {
            ((float4*)dst)[r] = make_float4(src[4 * r + 0], src[4 * r + 1],
                                            src[4 * r + 2], src[4 * r + 3]);
        }
    }
}

extern "C" void kernel_launch(void* const* d_in, const int* in_sizes, int n_in,
                              void* d_out, int out_size, void* d_ws, size_t ws_size,
                              hipStream_t stream) {
    const float* xyzs = (const float*)d_in[0];
    const float* wd   = (const float*)d_in[1];
    float* out_xyz = (float*)d_out;
    float* featp   = out_xyz + NB * NT * NM * 3;   // new_features region
    hipLaunchKernelGGL(fps_kernel, dim3(NB * NT), dim3(256), 0, stream, xyzs, out_xyz);
    hipLaunchKernelGGL(group_kernel, dim3(NB * NT * (NM / 16)), dim3(1024), 0, stream,
                       xyzs, wd, out_xyz, featp);
}